// Round 1
// baseline (29.571 us; speedup 1.0000x reference)
//
#include <hip/hip_runtime.h>
#include <hip/hip_bf16.h>

// out[b,y,x,o] = C * sum_c in[b, y/2, x/2, c], B=32,H=64,W=64,C=64,KH=KW=2
// Input  (32,64,64,64)  f32 = 33.5 MB
// Output (32,128,128,64) f32 = 134.2 MB
// One block per (b,h) input row: read 16KB coalesced, reduce 64 pixel-sums,
// broadcast-write two output rows (64KB) coalesced.

__global__ __launch_bounds__(256) void Conv2DTransposeNN_kernel(
    const float* __restrict__ in, float* __restrict__ out) {
    const int bid = blockIdx.x;          // bid = b*64 + h
    const int t   = threadIdx.x;

    __shared__ float s[64];              // per-pixel scaled sums

    // ---- Phase 1: read input row (1024 float4), per-pixel channel sums ----
    const float4* in4 = reinterpret_cast<const float4*>(in) + (size_t)bid * 1024;

    float partial[4];
#pragma unroll
    for (int j = 0; j < 4; ++j) {
        float4 v = in4[t + 256 * j];     // coalesced: contiguous per instruction
        partial[j] = (v.x + v.y) + (v.z + v.w);
    }
    // f4 index i = t + 256j covers pixel p = t/16 + 16j; reduce over the 16
    // consecutive lanes that share p (xor masks 1,2,4,8 stay in-group).
#pragma unroll
    for (int j = 0; j < 4; ++j) {
#pragma unroll
        for (int m = 1; m < 16; m <<= 1)
            partial[j] += __shfl_xor(partial[j], m);
    }
    if ((t & 15) == 0) {
        const int g = t >> 4;            // 0..15
#pragma unroll
        for (int j = 0; j < 4; ++j)
            s[g + 16 * j] = partial[j] * 64.0f;   // ×C
    }
    __syncthreads();

    // ---- Phase 2: write output rows y = 2h and 2h+1 ----
    const int b = bid >> 6;
    const int h = bid & 63;
    float4* out4 = reinterpret_cast<float4*>(out);
    // floats per output row = 128*64 = 8192 -> 2048 float4
    const size_t row0 = (size_t)(b * 128 + 2 * h) * 2048;

#pragma unroll
    for (int k = 0; k < 8; ++k) {
        const int i = t + 256 * k;       // f4 index within the row
        const float v = s[i >> 5];       // 32 lanes share one value: LDS broadcast
        const float4 val = make_float4(v, v, v, v);
        out4[row0 + i]        = val;     // row y = 2h
        out4[row0 + 2048 + i] = val;     // row y = 2h+1
    }
}

extern "C" void kernel_launch(void* const* d_in, const int* in_sizes, int n_in,
                              void* d_out, int out_size, void* d_ws, size_t ws_size,
                              hipStream_t stream) {
    const float* in = (const float*)d_in[0];
    float* out = (float*)d_out;
    // grid = B*H = 32*64 = 2048 blocks
    Conv2DTransposeNN_kernel<<<2048, 256, 0, stream>>>(in, out);
}